// Round 11
// baseline (226.334 us; speedup 1.0000x reference)
//
#include <hip/hip_runtime.h>
#include <hip/hip_bf16.h>
#include <math.h>

// ---------------------------------------------------------------------------
// EvidentialHead: x(8192x1024) -> silu(xW1+b1) -> LN -> silu(hW2+b2) -> W3+b3
//                 -> softplus head (alpha, evidence, expected_prob, vacuity,
//                    dissonance, aleatoric)
// R10->R11: LayerNorm FOLDED OUT. LN(h)W2 = a_r (h W2') + c_r u + v_beta with
// W2'=g-scaled W2, u=col-sums of W2', a_r=rsqrt(var+eps), c_r=-mu a_r.
// GEMM1 emits h1 fp16 plane + per-row (sum, sumsq) atomics (f32-acc stats);
// GEMM2 applies the fold in its epilogue. LN kernel + h1-f32 round trip gone.
// Pipeline: prep -> GEMM1(M3) -> GEMM2(M4) -> GEMM3(M1,split-K-8) -> head.
// fp16 GEMM core unchanged from R10 (chunked swizzled planes, gload_lds,
// BK=32 dbuf single-barrier, 512-thr blocks, conflict-free: R6/R9 = 0).
// ---------------------------------------------------------------------------

typedef __attribute__((ext_vector_type(8))) _Float16 f16x8;  // 8 fp16 (4 VGPRs)
typedef __attribute__((ext_vector_type(4))) float f32x4;

__device__ __forceinline__ unsigned short f2h(float v) {
  _Float16 h = (_Float16)v;             // RNE
  return *(unsigned short*)&h;
}

__device__ __forceinline__ void gld_lds16(const void* g, void* l) {
  // async global->LDS, 16B per lane; LDS dest = wave-uniform base + lane*16
  __builtin_amdgcn_global_load_lds((const __attribute__((address_space(1))) void*)g,
                                   (__attribute__((address_space(3))) void*)l, 16, 0, 0);
}

__device__ __forceinline__ float wred64(float v) {
#pragma unroll
  for (int m = 32; m >= 1; m >>= 1) v += __shfl_xor(v, m);
  return v;
}

__device__ __forceinline__ float digammaf_(float x) {
  // x > 1 always (alpha = softplus+1). Fixed 7-step shift to >= 8 (fast rcp),
  // then asymptotic series. rcp rel err ~1e-7 << output tolerance.
  float r = 0.f;
  if (x < 8.f) {
    r -= __builtin_amdgcn_rcpf(x);
    r -= __builtin_amdgcn_rcpf(x + 1.f);
    r -= __builtin_amdgcn_rcpf(x + 2.f);
    r -= __builtin_amdgcn_rcpf(x + 3.f);
    r -= __builtin_amdgcn_rcpf(x + 4.f);
    r -= __builtin_amdgcn_rcpf(x + 5.f);
    r -= __builtin_amdgcn_rcpf(x + 6.f);
    x += 7.f;
  }
  float inv = __builtin_amdgcn_rcpf(x), inv2 = inv * inv;
  float s = logf(x) - 0.5f * inv
          - inv2 * (0.083333333333f - inv2 * (0.008333333333f - inv2 * 0.003968253968f));
  return r + s;
}

// chunked-plane addressing (SWIZZLED): element (row r, k) of an Mx1024 operand:
//   chunk = (r>>7)*32 + (k>>5); within chunk (128x32 ushorts, 8KB):
//   off = (r&127)*32 + ((((k&31)>>3) ^ ((r>>1)&3))<<3) + (k&7)

// --- fused prep:
//  blocks [0,2176)      : W1/W2/W3 transpose+cvt (W2 g-scaled)
//  blocks [2176,6272)   : x cvt to plane
//  blocks [6272,6276)   : u[n] = sum_k g[k]W2[k][n]; bias2[n] = b2[n] + sum_k be[k]W2[k][n]
//  blocks [6276,6292)   : zero stats[8192][2]
__global__ __launch_bounds__(256) void prep_kernel(
    const float* __restrict__ W1, const float* __restrict__ W2,
    const float* __restrict__ W3, const float* __restrict__ x,
    const float* __restrict__ gw, const float* __restrict__ be,
    const float* __restrict__ b2,
    unsigned short* __restrict__ W1T, unsigned short* __restrict__ W2T,
    unsigned short* __restrict__ W3T, unsigned short* __restrict__ Xp,
    float* __restrict__ ub, float* __restrict__ bias2,
    float* __restrict__ stats) {
  __shared__ float t[32][33];
  const int b = blockIdx.x;
  const int tid = threadIdx.x;
  if (b < 2176) {
    // transpose+cvt one 32x32 tile of W[K=1024][Ncols] -> T[Npad][1024] plane
    const float* W; unsigned short* Th; int Ncols, idx; bool scale;
    if (b < 1024)      { W = W1; Th = W1T; Ncols = 1024; idx = b; scale = false; }
    else if (b < 2048) { W = W2; Th = W2T; Ncols = 1024; idx = b - 1024; scale = true; }
    else               { W = W3; Th = W3T; Ncols = 100;  idx = b - 2048; scale = false; }
    int k0 = (idx & 31) * 32, n0 = (idx >> 5) * 32;
#pragma unroll
    for (int i = 0; i < 4; ++i) {
      int e = i * 256 + tid;
      int r = e >> 5, c = e & 31;
      int gn = n0 + c;
      t[r][c] = (gn < Ncols) ? W[(size_t)(k0 + r) * Ncols + gn] : 0.f;
    }
    __syncthreads();
    int nr = tid >> 3, t2 = tid & 7;   // row n0+nr, k quad t2*4
    int kk = k0 + t2 * 4;
    float v0 = t[t2 * 4 + 0][nr], v1 = t[t2 * 4 + 1][nr];
    float v2 = t[t2 * 4 + 2][nr], v3 = t[t2 * 4 + 3][nr];
    if (scale) {  // W2' = g[k] * W2[k][n]
      v0 *= gw[kk + 0]; v1 *= gw[kk + 1]; v2 *= gw[kk + 2]; v3 *= gw[kk + 3];
    }
    ushort4 h;
    h.x = f2h(v0); h.y = f2h(v1); h.z = f2h(v2); h.w = f2h(v3);
    int n = n0 + nr;
    int q = t2 >> 1, half = t2 & 1;
    int qs = q ^ ((n >> 1) & 3);       // quad swizzle
    size_t base = ((size_t)(n >> 7) * 32 + (k0 >> 5)) * 4096
                + (n & 127) * 32 + (qs << 3) + (half << 2);
    *(ushort4*)(Th + base) = h;
  } else if (b < 6272) {
    // cvt x rows: 8 floats per thread
    int idx = (b - 2176) * 256 + tid;  // [0, 1M)
    int r = idx >> 7;
    int k0 = (idx & 127) * 8;          // 8-aligned: one full quad
    const float* sp = x + (size_t)r * 1024 + k0;
    const float4 v0 = *(const float4*)sp;
    const float4 v1 = *(const float4*)(sp + 4);
    ushort4 h0, h1;
    h0.x = f2h(v0.x); h0.y = f2h(v0.y); h0.z = f2h(v0.z); h0.w = f2h(v0.w);
    h1.x = f2h(v1.x); h1.y = f2h(v1.y); h1.z = f2h(v1.z); h1.w = f2h(v1.w);
    int q = (k0 & 31) >> 3;
    int qs = q ^ ((r >> 1) & 3);
    size_t base = ((size_t)(r >> 7) * 32 + (k0 >> 5)) * 4096
                + (r & 127) * 32 + (qs << 3);
    *(ushort4*)(Xp + base) = h0; *(ushort4*)(Xp + base + 4) = h1;
  } else if (b < 6276) {
    // u[n], bias2[n]; coalesced column sums of W2 (each block: 256 n's)
    int n = (b - 6272) * 256 + tid;
    float uu = 0.f, vb = 0.f;
    for (int k = 0; k < 1024; ++k) {
      float w = W2[(size_t)k * 1024 + n];
      uu += gw[k] * w;
      vb += be[k] * w;
    }
    ub[n] = uu;
    bias2[n] = b2[n] + vb;
  } else {
    // zero stats (8192*2 f32 = 4096 float4)
    int idx = (b - 6276) * 256 + tid;
    ((float4*)stats)[idx] = float4{0.f, 0.f, 0.f, 0.f};
  }
}

// --- fp16 GEMM, 16x16x32_f16 MFMA, 512 threads (8 waves of 32x64), BK=32,
// double-buffered single-barrier loop.
// MODE 1: split-K (blockIdx.z of 8, 128 K each), raw acc to C (ldc=100, col<100).
// MODE 3: full K, silu(acc+bias), emit fp16 plane + per-row (sum,sumsq) atomics.
// MODE 4: full K, LN-fold: silu(inv*acc + cS*u[col] + bias[col]), emit plane.
template <int MODE>
__global__ __launch_bounds__(512, 4) void gemm_f16(
    const unsigned short* __restrict__ Ap, const unsigned short* __restrict__ Bp,
    const float* __restrict__ bias, float* __restrict__ C,
    unsigned short* __restrict__ Op, const float* __restrict__ u,
    float* __restrict__ stats) {
  constexpr int NT = (MODE == 1) ? 4 : 32;             // K-tiles of 32
  __shared__ __align__(16) unsigned short lds[16384];  // 2 x (A 4096 | B 4096)
  const int tid = threadIdx.x;
  const int lane = tid & 63;
  const int wave = tid >> 6;        // 0..7
  const int wm = wave >> 1;         // 0..3: 32-row panel
  const int wn = wave & 1;          // 0..1: 64-col panel
  const int row0 = blockIdx.x * 128;
  const int col0 = blockIdx.y * 128;
  const int kbase = (MODE == 1) ? blockIdx.z * 4 : 0;  // in 32-k chunks
  const int lsrc = lane * 8;        // lane's 16B within a slot (ushort units)
  const size_t abase = (size_t)blockIdx.x * 32 * 4096;
  const size_t bbase = (size_t)blockIdx.y * 32 * 4096;

  f32x4 acc[2][4] = {};

  auto STAGE = [&](int bb, int t) {
    const size_t ac = abase + (size_t)(kbase + t) * 4096;
    const size_t bc = bbase + (size_t)(kbase + t) * 4096;
    const int lb = bb * 8192;
    const int so = wave * 512;      // one 1KB slot per wave per plane
    gld_lds16(Ap + ac + so + lsrc, &lds[lb + so]);
    gld_lds16(Bp + bc + so + lsrc, &lds[lb + 4096 + so]);
  };

  STAGE(0, 0);  // prologue prefetch
  for (int t = 0; t < NT; ++t) {
    __syncthreads();                       // drains vmcnt(0): buf[t&1] ready;
                                           // also: all reads of buf[(t+1)&1] done
    if (t + 1 < NT) STAGE((t + 1) & 1, t + 1);  // prefetch flies under MFMA below
    const int lb = (t & 1) * 8192;
    const int cc = lane >> 4;              // logical quad (16x16x32 A/B layout)
    f16x8 ah[2], bh[4];
#pragma unroll
    for (int a = 0; a < 2; ++a) {
      int r = wm * 32 + a * 16 + (lane & 15);
      int off = lb + r * 32 + ((cc ^ ((r >> 1) & 3)) << 3);  // swizzled read
      ah[a] = *(const f16x8*)&lds[off];
    }
#pragma unroll
    for (int b = 0; b < 4; ++b) {
      int n = wn * 64 + b * 16 + (lane & 15);
      int off = lb + 4096 + n * 32 + ((cc ^ ((n >> 1) & 3)) << 3);  // swizzled
      bh[b] = *(const f16x8*)&lds[off];
    }
#pragma unroll
    for (int a = 0; a < 2; ++a)
#pragma unroll
      for (int b = 0; b < 4; ++b)
        acc[a][b] = __builtin_amdgcn_mfma_f32_16x16x32_f16(ah[a], bh[b], acc[a][b], 0, 0, 0);
  }
  // epilogue: C/D layout col=lane&15, row=(lane>>4)*4+j  [m89/m91 verified]
  if (MODE == 1) {
#pragma unroll
    for (int a = 0; a < 2; ++a) {
      int rb = row0 + wm * 32 + a * 16 + (lane >> 4) * 4;
#pragma unroll
      for (int b = 0; b < 4; ++b) {
        int col = col0 + wn * 64 + b * 16 + (lane & 15);
        if (col < 100) {
          float* Cz = C + (size_t)blockIdx.z * 819200;
#pragma unroll
          for (int j = 0; j < 4; ++j)
            Cz[(size_t)(rb + j) * 100 + col] = acc[a][b][j];
        }
      }
    }
  } else {
#pragma unroll
    for (int a = 0; a < 2; ++a) {
      int rb = row0 + wm * 32 + a * 16 + (lane >> 4) * 4;
#pragma unroll
      for (int j = 0; j < 4; ++j) {
        int rr = rb + j;
        float inv = 0.f, cS = 0.f;
        if (MODE == 4) {
          float s1 = stats[(rr << 1) + 0], s2 = stats[(rr << 1) + 1];
          float mu = s1 * 0.0009765625f;
          float var = s2 * 0.0009765625f - mu * mu;
          inv = rsqrtf(var + 1e-5f);
          cS = -mu * inv;
        }
        float vs = 0.f, vq = 0.f;
        const size_t rbase = (size_t)blockIdx.x * 32 * 4096 + (size_t)(rr & 127) * 32;
        const int rsw = (rr >> 1) & 3;
#pragma unroll
        for (int b = 0; b < 4; ++b) {
          int col = col0 + wn * 64 + b * 16 + (lane & 15);
          float v;
          if (MODE == 4) v = inv * acc[a][b][j] + cS * u[col] + bias[col];
          else           v = acc[a][b][j] + bias[col];
          v = v / (1.f + expf(-v));  // silu
          int q = (col & 31) >> 3, p = col & 7;
          size_t base = rbase + (size_t)(col >> 5) * 4096 + ((q ^ rsw) << 3) + p;
          Op[base] = f2h(v);
          if (MODE == 3) { vs += v; vq += v * v; }
        }
        if (MODE == 3) {
          // reduce across the 16 lanes sharing this row (lane>>4 fixed)
#pragma unroll
          for (int m = 1; m <= 8; m <<= 1) {
            vs += __shfl_xor(vs, m);
            vq += __shfl_xor(vq, m);
          }
          if ((lane & 15) == 0) {
            atomicAdd(&stats[(rr << 1) + 0], vs);
            atomicAdd(&stats[(rr << 1) + 1], vq);
          }
        }
      }
    }
  }
}

// --- Evidential head: sums 8 split-K partials + b3, per row (K=100), wave/row.
// Dissonance via cyclic half-pairing: dissonance = 0.5*sum_offdiag(term)
//   = sum_{d=1..49} T_d + 0.5*T_50,  T_d = sum_i term(i, (i+d)%100).
// Belief array mirrored (bel[100+t]=bel[t], zero tail) so j=i+d never wraps.
__global__ __launch_bounds__(256) void head_kernel(
    const float* __restrict__ part, const float* __restrict__ b3,
    float* __restrict__ out) {
  __shared__ float bel[4][184];
  int tid = threadIdx.x;
  int wave = tid >> 6, lane = tid & 63;
  int row = blockIdx.x * 4 + wave;
  size_t rb = (size_t)row * 100;
  bool v1 = lane < 36;  // second element index lane+64 in [64,100)
  float l0 = b3[lane];
  float l1 = v1 ? b3[lane + 64] : 0.f;
#pragma unroll
  for (int z = 0; z < 8; ++z) {
    const float* pz = part + (size_t)z * 819200 + rb;
    l0 += pz[lane];
    if (v1) l1 += pz[lane + 64];
  }
  float e0 = fmaxf(l0, 0.f) + log1pf(expf(-fabsf(l0)));  // softplus
  float e1 = fmaxf(l1, 0.f) + log1pf(expf(-fabsf(l1)));
  float a0 = e0 + 1.f, a1 = e1 + 1.f;
  float S = 100.f + wred64(e0 + (v1 ? e1 : 0.f));
  float invS = 1.f / S;
  float b0 = e0 * invS;
  float b1 = v1 ? e1 * invS : 0.f;
  bel[wave][lane] = b0;                                   // [0,64)
  if (v1) bel[wave][lane + 64] = b1;                      // [64,100)
  bel[wave][lane + 100] = (lane < 50) ? b0 : 0.f;         // mirror [100,150) + zeros
  if (lane < 16) bel[wave][lane + 164] = 0.f;             // zeros (junk-lane reads)
  __syncthreads();
  const float* bp = &bel[wave][0];
  float b0e = b0 + 1e-8f;
  float b1e = b1 + 1e-8f;
  float acc = 0.f;
#pragma unroll
  for (int d = 1; d <= 50; ++d) {
    float bj0 = bp[lane + d];          // ds_read base+imm offset (unrolled)
    float bj1 = bp[lane + 64 + d];     // junk lanes read zeros; b1=0 kills term
    float p0 = b0 * bj0;
    float p1 = b1 * bj1;
    float q0 = p0 * fabsf(b0 - bj0);   // abs folds into src modifier
    float q1 = p1 * fabsf(b1 - bj1);
    float r0 = __builtin_amdgcn_rcpf(b0e + bj0);
    float r1 = __builtin_amdgcn_rcpf(b1e + bj1);
    float t = (p0 - q0 * r0) + (p1 - q1 * r1);
    acc += (d == 50) ? 0.5f * t : t;   // compile-time select (unrolled)
  }
  float diss = wred64(acc);
  float dgS = digammaf_(S);
  float t0 = a0 * invS * (digammaf_(a0) - dgS);
  float t1 = v1 ? a1 * invS * (digammaf_(a1) - dgS) : 0.f;
  float ale = -wred64(t0 + t1);
  // outputs: alpha | evidence | expected_prob | vacuity | dissonance | aleatoric
  out[rb + lane] = a0;
  out[819200 + rb + lane] = e0;
  out[1638400 + rb + lane] = a0 * invS;
  if (v1) {
    out[rb + lane + 64] = a1;
    out[819200 + rb + lane + 64] = e1;
    out[1638400 + rb + lane + 64] = a1 * invS;
  }
  if (lane == 0) {
    out[2457600 + row] = 100.f * invS;
    out[2457600 + 8192 + row] = diss;
    out[2457600 + 16384 + row] = ale;
  }
}

extern "C" void kernel_launch(void* const* d_in, const int* in_sizes, int n_in,
                              void* d_out, int out_size, void* d_ws, size_t ws_size,
                              hipStream_t stream) {
  const float* x  = (const float*)d_in[0];
  const float* W1 = (const float*)d_in[1];
  const float* b1 = (const float*)d_in[2];
  const float* g  = (const float*)d_in[3];
  const float* be = (const float*)d_in[4];
  const float* W2 = (const float*)d_in[5];
  const float* b2 = (const float*)d_in[6];
  const float* W3 = (const float*)d_in[7];
  const float* b3 = (const float*)d_in[8];
  float* out = (float*)d_out;

  // workspace (peak 73 MB), phase-based reuse (no RAW overlap, audited):
  //  R0 [0,32M)   : x-plane fp16 (16M) -> split-K partials (26.2M, after GEMM2)
  //  [32,37M)     : W1T (2M), W2T g-scaled (2M), W3T (0.25M)
  //  [37M,+72K)   : stats[8192][2] f32 (64K), u (4K), bias2 (4K)
  //  R1 [41,73M)  : h1 plane fp16 (16M) @41M, h2 plane fp16 (16M) @57M
  char* w = (char*)d_ws;
  unsigned short* Xp    = (unsigned short*)(w);
  unsigned short* W1T   = (unsigned short*)(w + (32ll << 20));
  unsigned short* W2T   = (unsigned short*)(w + (34ll << 20));
  unsigned short* W3T   = (unsigned short*)(w + (36ll << 20));
  float*          stats = (float*)(w + (37ll << 20));
  float*          ub    = (float*)(w + (37ll << 20) + (64ll << 10));
  float*          bias2 = (float*)(w + (37ll << 20) + (68ll << 10));
  unsigned short* H1p   = (unsigned short*)(w + (41ll << 20));
  unsigned short* H2p   = (unsigned short*)(w + (57ll << 20));
  float*          parts = (float*)(w);   // over dead x-plane (after GEMM2)

  dim3 blk(256);
  dim3 blk512(512);
  // prep: W tiles [0,2176), x-cvt [2176,6272), u/bias2 [6272,6276), stats-zero [6276,6292)
  hipLaunchKernelGGL(prep_kernel, dim3(6292), blk, 0, stream,
                     W1, W2, W3, x, g, be, b2, W1T, W2T, W3T, Xp, ub, bias2, stats);
  // GEMM1 (MODE 3): x-plane * W1T -> silu -> h1 plane + row stats atomics
  hipLaunchKernelGGL((gemm_f16<3>), dim3(64, 8), blk512, 0, stream,
                     Xp, W1T, b1, (float*)nullptr, H1p, (const float*)nullptr, stats);
  // GEMM2 (MODE 4): h1 plane * W2T' with LN fold -> silu -> h2 plane
  hipLaunchKernelGGL((gemm_f16<4>), dim3(64, 8), blk512, 0, stream,
                     H1p, W2T, bias2, (float*)nullptr, H2p, ub, stats);
  // GEMM3 (MODE 1, split-K-8): h2 plane * W3T -> partials into R0
  hipLaunchKernelGGL((gemm_f16<1>), dim3(64, 1, 8), blk512, 0, stream,
                     H2p, W3T, (const float*)nullptr, parts, (unsigned short*)nullptr,
                     (const float*)nullptr, (float*)nullptr);
  hipLaunchKernelGGL(head_kernel, dim3(2048), blk, 0, stream, parts, b3, out);
  (void)in_sizes; (void)n_in; (void)out_size; (void)ws_size;
}